// Round 3
// baseline (807.778 us; speedup 1.0000x reference)
//
#include <hip/hip_runtime.h>
#include <math.h>

// ---- problem constants (static per reference) ----
#define D_MODEL   256
#define N_HEADS   8
#define HEAD_DIM  32
#define N_LEVELS  3
#define N_POINTS  2
#define BS        16
#define NQ        900
#define LEN_IN    13125
#define M_Q       (BS * NQ * N_LEVELS)   // 43200
#define M_V       (BS * LEN_IN)          // 210000

typedef _Float16 f16x8 __attribute__((ext_vector_type(8)));
typedef _Float16 f16x4 __attribute__((ext_vector_type(4)));
typedef float f32x4 __attribute__((ext_vector_type(4)));

// ---------------------------------------------------------------------------
// Weight prep: W[K=256][N] fp32  ->  Wt_hi[n][k], Wt_lo[n][k] fp16 split.
// Rows n in [N, Npad) are zero-filled.  idx = n*256 + k.
// ---------------------------------------------------------------------------
__global__ __launch_bounds__(256) void convert_weight_kernel(
    const float* __restrict__ W, _Float16* __restrict__ Wth,
    _Float16* __restrict__ Wtl, int N, int Npad) {
  const int idx = blockIdx.x * 256 + threadIdx.x;
  if (idx >= Npad * 256) return;
  const int n = idx >> 8;
  const int k = idx & 255;
  const float v = (n < N) ? W[(size_t)k * N + n] : 0.0f;
  const _Float16 h = (_Float16)v;
  Wth[idx] = h;
  Wtl[idx] = (_Float16)(v - (float)h);
}

// ---------------------------------------------------------------------------
// C[M,N] = A[M,256] @ W[256,N] + bias  via fp16x3 split MFMA.
//   A fp32, converted to hi/lo fp16 during LDS staging.
//   Weights pre-split/transposed: Bth/Btl[n][k] fp16, n-padded to BN.
// Block: 64 rows x BN cols, 256 threads = 4 waves side by side (BN/4 cols each).
// K-step 32 = one v_mfma_f32_16x16x32_f16.
// Fragment mapping (guide-verified family): lane&15 selects row/col,
// (lane>>4)*8 + j selects k;  C/D: col=lane&15, row=(lane>>4)*4+reg.
// ---------------------------------------------------------------------------
template <int BN>
__global__ __launch_bounds__(256) void gemm_mfma_f16x3_kernel(
    const float* __restrict__ A, const _Float16* __restrict__ Bth,
    const _Float16* __restrict__ Btl, const float* __restrict__ bias,
    float* __restrict__ C, int M, int N) {
  constexpr int K = 256;
  constexpr int BK = 32;
  constexpr int FC = BN / 64;   // 16-wide col fragments per wave
  // rows padded to 40 halfs (80 B = 5*16 B): 16B-aligned b128, ~2-way banks
  __shared__ _Float16 Ah[64][40];
  __shared__ _Float16 Al[64][40];
  __shared__ _Float16 Bh[BN][40];
  __shared__ _Float16 Bl[BN][40];

  const int tid = threadIdx.x;
  const int wid = tid >> 6;
  const int lane = tid & 63;
  const int bm = blockIdx.x * 64;

  const int a_row0 = tid >> 3;         // 0..31
  const int a_k4 = (tid & 7) * 4;      // 0,4,..,28

  f32x4 acc[4][FC];
#pragma unroll
  for (int fr = 0; fr < 4; ++fr)
#pragma unroll
    for (int fc = 0; fc < FC; ++fc) acc[fr][fc] = (f32x4)0.0f;

  const int khi = (lane >> 4) * 8;
  const int rsel = lane & 15;

  for (int k0 = 0; k0 < K; k0 += BK) {
    // ---- stage A tile (64 x 32 fp32 -> hi/lo fp16), coalesced float4 ----
#pragma unroll
    for (int it = 0; it < 2; ++it) {
      const int row = a_row0 + it * 32;
      float4 v = make_float4(0.f, 0.f, 0.f, 0.f);
      if (bm + row < M)
        v = *reinterpret_cast<const float4*>(
            &A[(size_t)(bm + row) * K + k0 + a_k4]);
      f16x4 h, l;
      h[0] = (_Float16)v.x; l[0] = (_Float16)(v.x - (float)h[0]);
      h[1] = (_Float16)v.y; l[1] = (_Float16)(v.y - (float)h[1]);
      h[2] = (_Float16)v.z; l[2] = (_Float16)(v.z - (float)h[2]);
      h[3] = (_Float16)v.w; l[3] = (_Float16)(v.w - (float)h[3]);
      *reinterpret_cast<f16x4*>(&Ah[row][a_k4]) = h;
      *reinterpret_cast<f16x4*>(&Al[row][a_k4]) = l;
    }
    // ---- stage B tile (BN x 32 fp16 hi/lo), b128 copies ----
#pragma unroll
    for (int it = 0; it < BN / 64; ++it) {
      const int i = tid + 256 * it;
      const int col = i >> 2;
      const int k8 = (i & 3) * 8;
      *reinterpret_cast<f16x8*>(&Bh[col][k8]) =
          *reinterpret_cast<const f16x8*>(&Bth[(size_t)col * K + k0 + k8]);
      *reinterpret_cast<f16x8*>(&Bl[col][k8]) =
          *reinterpret_cast<const f16x8*>(&Btl[(size_t)col * K + k0 + k8]);
    }
    __syncthreads();

    // ---- fragments ----
    f16x8 afh[4], afl[4], bfh[FC], bfl[FC];
#pragma unroll
    for (int fr = 0; fr < 4; ++fr) {
      afh[fr] = *reinterpret_cast<const f16x8*>(&Ah[fr * 16 + rsel][khi]);
      afl[fr] = *reinterpret_cast<const f16x8*>(&Al[fr * 16 + rsel][khi]);
    }
#pragma unroll
    for (int fc = 0; fc < FC; ++fc) {
      const int c = wid * (BN / 4) + fc * 16 + rsel;
      bfh[fc] = *reinterpret_cast<const f16x8*>(&Bh[c][khi]);
      bfl[fc] = *reinterpret_cast<const f16x8*>(&Bl[c][khi]);
    }
    // ---- 3-term split MFMA:  Ah*Bh + Ah*Bl + Al*Bh ----
#pragma unroll
    for (int fr = 0; fr < 4; ++fr)
#pragma unroll
      for (int fc = 0; fc < FC; ++fc) {
        acc[fr][fc] = __builtin_amdgcn_mfma_f32_16x16x32_f16(
            afh[fr], bfh[fc], acc[fr][fc], 0, 0, 0);
        acc[fr][fc] = __builtin_amdgcn_mfma_f32_16x16x32_f16(
            afh[fr], bfl[fc], acc[fr][fc], 0, 0, 0);
        acc[fr][fc] = __builtin_amdgcn_mfma_f32_16x16x32_f16(
            afl[fr], bfh[fc], acc[fr][fc], 0, 0, 0);
      }
    __syncthreads();
  }

  // ---- store with bias ----
#pragma unroll
  for (int fr = 0; fr < 4; ++fr) {
#pragma unroll
    for (int i = 0; i < 4; ++i) {
      const int row = bm + fr * 16 + (lane >> 4) * 4 + i;
      if (row >= M) continue;
#pragma unroll
      for (int fc = 0; fc < FC; ++fc) {
        const int col = wid * (BN / 4) + fc * 16 + rsel;
        if (col < N)
          C[(size_t)row * N + col] = acc[fr][fc][i] + bias[col];
      }
    }
  }
}

// ---------------------------------------------------------------------------
// Fused softmax + bilinear sampling + attention-weighted accumulation.
// One block per (b, q, fl) row; 256 threads = 8 heads x 32 dims.
// ---------------------------------------------------------------------------
__global__ __launch_bounds__(256) void sample_kernel(
    const float* __restrict__ value, const float* __restrict__ refpts,
    const float* __restrict__ offs, const float* __restrict__ attn,
    float* __restrict__ out_mid) {
  const int row = blockIdx.x;            // b*2700 + q*3 + fl
  const int tid = threadIdx.x;
  const int h = tid >> 5;
  const int d = tid & 31;
  const int b = row / (NQ * N_LEVELS);

  const int LVL_W[3] = {100, 50, 25};
  const int LVL_H[3] = {100, 50, 25};
  const int LVL_BASE[3] = {0, 10000, 12500};

  const float* off_p  = offs + (size_t)row * 96 + h * 12;
  const float* attn_p = attn + (size_t)row * 48 + h * 6;

  float aw[6];
  float mx = -INFINITY;
#pragma unroll
  for (int j = 0; j < 6; ++j) {
    aw[j] = attn_p[j];
    mx = fmaxf(mx, aw[j]);
  }
  float ssum = 0.f;
#pragma unroll
  for (int j = 0; j < 6; ++j) {
    aw[j] = expf(aw[j] - mx);
    ssum += aw[j];
  }
  const float rs = 1.0f / ssum;

  const float rx = refpts[(size_t)row * 2 + 0];
  const float ry = refpts[(size_t)row * 2 + 1];

  const float* vbase = value + (size_t)b * LEN_IN * 256 + h * 32 + d;
  float acc = 0.f;

#pragma unroll
  for (int l = 0; l < N_LEVELS; ++l) {
    const int W = LVL_W[l], base = LVL_BASE[l];
    const float fW = (float)LVL_W[l], fH = (float)LVL_H[l];
#pragma unroll
    for (int p = 0; p < N_POINTS; ++p) {
      const float ox = off_p[(l * 2 + p) * 2 + 0];
      const float oy = off_p[(l * 2 + p) * 2 + 1];
      const float x = (rx + ox / fW) * fW - 0.5f;
      const float y = (ry + oy / fH) * fH - 0.5f;
      const float x0 = floorf(x);
      const float y0 = floorf(y);
      const float wa = aw[l * 2 + p] * rs;
#pragma unroll
      for (int dy = 0; dy < 2; ++dy) {
#pragma unroll
        for (int dx = 0; dx < 2; ++dx) {
          const float xi = x0 + (float)dx;
          const float yi = y0 + (float)dy;
          const float wgt = (1.0f - fabsf(x - xi)) * (1.0f - fabsf(y - yi));
          const bool valid = (xi >= 0.f) && (xi <= fW - 1.f) &&
                             (yi >= 0.f) && (yi <= fH - 1.f);
          const int xic = (int)fminf(fmaxf(xi, 0.f), fW - 1.f);
          const int yic = (int)fminf(fmaxf(yi, 0.f), fH - 1.f);
          const int pos = base + yic * W + xic;
          const float g = vbase[(size_t)pos * 256];
          acc = fmaf(g, valid ? wgt * wa : 0.0f, acc);
        }
      }
    }
  }
  out_mid[(size_t)row * 256 + tid] = acc;
}

// ---------------------------------------------------------------------------
extern "C" void kernel_launch(void* const* d_in, const int* in_sizes, int n_in,
                              void* d_out, int out_size, void* d_ws,
                              size_t ws_size, hipStream_t stream) {
  const float* query   = (const float*)d_in[0];   // [16,900,3,256]
  const float* refpts  = (const float*)d_in[1];   // [16,900,3,2]
  const float* in_flat = (const float*)d_in[2];   // [16,13125,256]
  // d_in[3]: spatial shapes (static, hardcoded)
  const float* W_value = (const float*)d_in[4];
  const float* b_value = (const float*)d_in[5];
  const float* W_off   = (const float*)d_in[6];
  const float* b_off   = (const float*)d_in[7];
  const float* W_attn  = (const float*)d_in[8];
  const float* b_attn  = (const float*)d_in[9];
  const float* W_out   = (const float*)d_in[10];
  const float* b_out   = (const float*)d_in[11];
  float* out = (float*)d_out;

  char* ws = (char*)d_ws;
  float* value   = (float*)ws; ws += (size_t)M_V * 256 * sizeof(float);
  float* out_mid = (float*)ws; ws += (size_t)M_Q * 256 * sizeof(float);
  float* offs    = (float*)ws; ws += (size_t)M_Q * 96 * sizeof(float);
  float* attn    = (float*)ws; ws += (size_t)M_Q * 48 * sizeof(float);
  _Float16* Wvh = (_Float16*)ws; ws += 256 * 256 * sizeof(_Float16);
  _Float16* Wvl = (_Float16*)ws; ws += 256 * 256 * sizeof(_Float16);
  _Float16* Woh = (_Float16*)ws; ws += 256 * 256 * sizeof(_Float16);
  _Float16* Wol = (_Float16*)ws; ws += 256 * 256 * sizeof(_Float16);
  _Float16* Wfh = (_Float16*)ws; ws += 128 * 256 * sizeof(_Float16);  // W_off pad->128
  _Float16* Wfl = (_Float16*)ws; ws += 128 * 256 * sizeof(_Float16);
  _Float16* Wah = (_Float16*)ws; ws += 128 * 256 * sizeof(_Float16);  // W_attn pad->128
  _Float16* Wal = (_Float16*)ws; ws += 128 * 256 * sizeof(_Float16);

  const dim3 blk(256);

  // ---- weight prep (tiny) ----
  convert_weight_kernel<<<dim3(256), blk, 0, stream>>>(W_value, Wvh, Wvl, 256, 256);
  convert_weight_kernel<<<dim3(256), blk, 0, stream>>>(W_out,   Woh, Wol, 256, 256);
  convert_weight_kernel<<<dim3(128), blk, 0, stream>>>(W_off,   Wfh, Wfl,  96, 128);
  convert_weight_kernel<<<dim3(128), blk, 0, stream>>>(W_attn,  Wah, Wal,  48, 128);

  // 1) value = input_flatten @ W_value + b_value   (210000 x 256 x 256)
  gemm_mfma_f16x3_kernel<256>
      <<<dim3((M_V + 63) / 64), blk, 0, stream>>>(
          in_flat, Wvh, Wvl, b_value, value, M_V, 256);

  // 2a) offset logits = query @ W_off + b_off   (N=96)
  gemm_mfma_f16x3_kernel<128>
      <<<dim3((M_Q + 63) / 64), blk, 0, stream>>>(
          query, Wfh, Wfl, b_off, offs, M_Q, 96);

  // 2b) attn logits = query @ W_attn + b_attn   (N=48)
  gemm_mfma_f16x3_kernel<128>
      <<<dim3((M_Q + 63) / 64), blk, 0, stream>>>(
          query, Wah, Wal, b_attn, attn, M_Q, 48);

  // 3) softmax + bilinear sampling + weighted sum -> out_mid
  sample_kernel<<<dim3(M_Q), blk, 0, stream>>>(value, refpts, offs, attn,
                                               out_mid);

  // 4) out = out_mid @ W_out + b_out   (43200 x 256 x 256)
  gemm_mfma_f16x3_kernel<256>
      <<<dim3((M_Q + 63) / 64), blk, 0, stream>>>(
          out_mid, Woh, Wol, b_out, out, M_Q, 256);
}